// Round 7
// baseline (574.130 us; speedup 1.0000x reference)
//
#include <hip/hip_runtime.h>
#include <hip/hip_cooperative_groups.h>
#include <math.h>

namespace cg = cooperative_groups;

#define SEQ 2048
#define DIM 1024

typedef __attribute__((ext_vector_type(8))) _Float16 half8;
typedef __attribute__((ext_vector_type(4))) float f32x4;

__device__ __forceinline__ unsigned short f2h(float f) {
    union { _Float16 h; unsigned short u; } c; c.h = (_Float16)f;
    return c.u;
}
__device__ __forceinline__ float gmask(int k) {
    float t = ((float)k - 1024.0f) * (1.0f / 512.0f);
    return expf(-0.5f * t * t);
}
__device__ __forceinline__ void glds16(const unsigned short* gp, unsigned short* lp) {
    __builtin_amdgcn_global_load_lds((const __attribute__((address_space(1))) void*)gp,
                                     (__attribute__((address_space(3))) void*)lp, 16, 0, 0);
}

// Stage a 128x64 fp16 tile (16 KB) into lds. Row r = 64 elems (8 slots of
// 16B); LDS slot g^(r&7) holds global seg g. With the 16x16 fragment read
// pattern below this measured 0 bank conflicts (r4/r6); the 32x32 pattern
// (r5) conflicted — do not switch back.
__device__ __forceinline__ void stage64(const unsigned short* __restrict__ g, int ldK,
                                        unsigned short* lds, int wave, int lane) {
    int row = wave * 32 + (lane >> 3);
    int seg = (lane & 7) ^ (lane >> 3);
    const unsigned short* gp = g + (long)row * ldK + seg * 8;
    unsigned short* lp = lds + wave * 2048;
    glds16(gp, lp);
    glds16(gp + 8 * (long)ldK, lp + 512);
    glds16(gp + 16 * (long)ldK, lp + 1024);
    glds16(gp + 24 * (long)ldK, lp + 1536);
}

enum { EPI_QKV = 0, EPI_EXP = 1, EPI_PV = 2, EPI_OUT = 3 };

// One 128x128 output tile of C = A @ B^T (16x16x32 fp16 MFMA, BK=64).
// EPI_QKV: N=3072 packed; writes Q, K, V^T [b][d][s] (+bias).
// EPI_EXP: writes fp16 exp(acc*scale*gmask(n)).
// EPI_PV : self-normalizing PV; A (expS) row sums accumulated from LDS.
// EPI_OUT: writes fp32 acc + bias(n).
template <int EPI>
__device__ __forceinline__ void gemm_tile(
    unsigned short* As, unsigned short* Bs, int tid,
    int tm, int tn, int bz,
    const unsigned short* __restrict__ A, const unsigned short* __restrict__ Bm,
    const float* __restrict__ bias,
    float* __restrict__ Cf, unsigned short* __restrict__ Ch,
    int N, int K, float scale, long sA, long sB, long sC)
{
    const int wave = tid >> 6;
    const int lane = tid & 63;
    const int wm = (wave & 1) * 64;
    const int wn = (wave >> 1) * 64;
    const long m0 = (long)tm * 128;
    const long n0 = (long)tn * 128;
    const int lm = lane & 15;
    const int lk = lane >> 4;

    const unsigned short* pA = A + bz * sA + m0 * K;
    const unsigned short* pB = Bm + bz * sB + n0 * K;

    f32x4 acc[4][4];
#pragma unroll
    for (int i = 0; i < 4; ++i)
#pragma unroll
        for (int j = 0; j < 4; ++j) {
            acc[i][j].x = 0.f; acc[i][j].y = 0.f; acc[i][j].z = 0.f; acc[i][j].w = 0.f;
        }

    int aoff[4][2], boff[4][2];
#pragma unroll
    for (int i = 0; i < 4; ++i)
#pragma unroll
        for (int t = 0; t < 2; ++t) {
            int ar = wm + i * 16 + lm;
            aoff[i][t] = ar * 64 + (((4 * t + lk) ^ (ar & 7)) << 3);
            int br = wn + i * 16 + lm;
            boff[i][t] = br * 64 + (((4 * t + lk) ^ (br & 7)) << 3);
        }

    // PV row-sum: thread sums half the slots of one local row
    const int pr = (wave & 1) * 64 + lane;
    const int ph = wave >> 1;
    float psum = 0.f;

    for (int k0 = 0; k0 < K; k0 += 64) {
        stage64(pA + k0, K, As, wave, lane);
        stage64(pB + k0, K, Bs, wave, lane);
        __syncthreads();

        if (EPI == EPI_PV) {
            const unsigned short* rowp = As + pr * 64;
#pragma unroll
            for (int i2 = 0; i2 < 4; ++i2) {
                half8 h = *(const half8*)(rowp + (((2 * i2 + ph) ^ (pr & 7)) << 3));
#pragma unroll
                for (int e = 0; e < 8; ++e) psum += (float)h[e];
            }
        }

#pragma unroll
        for (int t = 0; t < 2; ++t) {
            half8 a[4], b[4];
#pragma unroll
            for (int i = 0; i < 4; ++i) a[i] = *(const half8*)(As + aoff[i][t]);
#pragma unroll
            for (int j = 0; j < 4; ++j) b[j] = *(const half8*)(Bs + boff[j][t]);
#pragma unroll
            for (int i = 0; i < 4; ++i)
#pragma unroll
                for (int j = 0; j < 4; ++j)
                    acc[i][j] = __builtin_amdgcn_mfma_f32_16x16x32_f16(a[i], b[j], acc[i][j], 0, 0, 0);
        }
        __syncthreads();
    }

    float* rsf = (float*)As;
    if (EPI == EPI_PV) {
        rsf[ph * 128 + pr] = psum;
        __syncthreads();
    }

    // epilogue. C/D layout: col = lane&15, row = (lane>>4)*4 + r  [m89/m91]
    const long MD = 8388608;  // 4*SEQ*DIM
    float* cF = (EPI == EPI_OUT) ? Cf + bz * sC : (float*)nullptr;
    unsigned short* cH = (EPI != EPI_OUT) ? Ch + bz * sC : (unsigned short*)nullptr;

#pragma unroll
    for (int i = 0; i < 4; ++i) {
        long mrow = m0 + wm + i * 16 + lk * 4;
        int lr = wm + i * 16 + lk * 4;
        float inv4[4];
        if (EPI == EPI_PV) {
#pragma unroll
            for (int r = 0; r < 4; ++r)
                inv4[r] = 1.0f / (rsf[lr + r] + rsf[128 + lr + r]);
        }
#pragma unroll
        for (int j = 0; j < 4; ++j) {
            int n = (int)n0 + wn + j * 16 + lm;
            if (EPI == EPI_QKV) {
                int sel = n >> 10;   // block-uniform
                int n1 = n & 1023;
                float bs = bias[n];
                if (sel < 2) {
                    unsigned short* dst = cH + (long)sel * MD;
#pragma unroll
                    for (int r = 0; r < 4; ++r)
                        dst[(mrow + r) * (long)DIM + n1] = f2h(acc[i][j][r] + bs);
                } else {
                    long b = mrow >> 11, s = mrow & 2047;
                    long idx = 2 * MD + b * (long)DIM * SEQ + (long)n1 * SEQ + s;
                    unsigned long long pk =
                        (unsigned long long)f2h(acc[i][j].x + bs) |
                        ((unsigned long long)f2h(acc[i][j].y + bs) << 16) |
                        ((unsigned long long)f2h(acc[i][j].z + bs) << 32) |
                        ((unsigned long long)f2h(acc[i][j].w + bs) << 48);
                    *(unsigned long long*)(cH + idx) = pk;
                }
            } else if (EPI == EPI_EXP) {
                float mult = scale * gmask(n);
#pragma unroll
                for (int r = 0; r < 4; ++r)
                    cH[(mrow + r) * (long)N + n] = f2h(expf(acc[i][j][r] * mult));
            } else if (EPI == EPI_PV) {
#pragma unroll
                for (int r = 0; r < 4; ++r)
                    cH[(mrow + r) * (long)N + n] = f2h(acc[i][j][r] * inv4[r]);
            } else {  // EPI_OUT
                float bs = bias[n];
#pragma unroll
                for (int r = 0; r < 4; ++r)
                    cF[(mrow + r) * (long)N + n] = acc[i][j][r] + bs;
            }
        }
    }
}

// Single cooperative kernel: prep | QKV | EXP | PV | OUT with grid syncs.
__global__ __launch_bounds__(256, 4) void mega(
    const float* __restrict__ x,
    const float* __restrict__ Wq, const float* __restrict__ bq,
    const float* __restrict__ Wk, const float* __restrict__ bk,
    const float* __restrict__ Wv, const float* __restrict__ bv,
    const float* __restrict__ Wo, const float* __restrict__ bo,
    void* __restrict__ ws, float* __restrict__ out)
{
    __shared__ unsigned short As[128 * 64];
    __shared__ unsigned short Bs[128 * 64];

    const long MD = 8388608;     // 4*SEQ*DIM
    const long WW = 1048576;     // DIM*DIM
    const long SD = (long)SEQ * DIM, SS = (long)SEQ * SEQ;

    unsigned short* xh   = (unsigned short*)ws;            // 16 MB
    unsigned short* Wp   = xh + MD;                        // 8 MB fp16 (Wq|Wk|Wv|Wo)
    unsigned short* Woh  = Wp + 3 * WW;
    float* bqkv          = (float*)(Wp + 4 * WW);          // 3072 (+pad)
    unsigned short* Qh   = (unsigned short*)(bqkv + 4096); // Q|K|VT contiguous 48 MB
    unsigned short* VT   = Qh + 2 * MD;
    unsigned short* expS = Qh + 3 * MD;                    // 32 MB
    unsigned short* O1   = xh;                             // alias: x dead after QKV

    cg::grid_group grid = cg::this_grid();
    const int tid = threadIdx.x;
    const int bid = blockIdx.x;
    const int nblk = gridDim.x;

    // ---- phase 0: prep (x->fp16, pack weights fp16, pack qkv bias)
    {
        long gid = (long)bid * 256 + tid;
        if (gid < 3072) {
            int sel = (int)(gid >> 10);
            const float* s = sel == 0 ? bq : sel == 1 ? bk : bv;
            bqkv[gid] = s[gid & 1023];
        }
        const long NX = MD / 4;        // x float4 count
        const long NW = WW / 4;        // per-weight float4 count (2^18)
        const long total = NX + 4 * NW;
        for (long i = gid; i < total; i += (long)nblk * 256) {
            const float* src; unsigned short* dst; long off;
            if (i < NX) { src = x; dst = xh; off = i; }
            else {
                long wi = i - NX;
                int sel = (int)(wi >> 18);
                src = sel == 0 ? Wq : sel == 1 ? Wk : sel == 2 ? Wv : Wo;
                dst = Wp + ((long)sel << 20);
                off = wi & (NW - 1);
            }
            float4 v = ((const float4*)src)[off];
            unsigned long long p = (unsigned long long)f2h(v.x) | ((unsigned long long)f2h(v.y) << 16) |
                                   ((unsigned long long)f2h(v.z) << 32) | ((unsigned long long)f2h(v.w) << 48);
            ((unsigned long long*)dst)[off] = p;
        }
    }
    grid.sync();

    // ---- phase 1: QKV fused GEMM, 64 x 24 = 1536 tiles
    for (int t = bid; t < 1536; t += nblk)
        gemm_tile<EPI_QKV>(As, Bs, tid, t & 63, t >> 6, 0,
                           xh, Wp, bqkv, nullptr, Qh, 3 * DIM, DIM, 1.0f, 0, 0, 0);
    grid.sync();

    // ---- phase 2: expS = exp(QK^T/32 * gmask), 16 x 16 x 4 = 1024 tiles
    for (int t = bid; t < 1024; t += nblk)
        gemm_tile<EPI_EXP>(As, Bs, tid, (t >> 4) & 15, t & 15, t >> 8,
                           Qh, Qh + MD, nullptr, nullptr, expS, SEQ, DIM, 0.03125f, SD, SD, SS);
    grid.sync();

    // ---- phase 3: O1 = (expS @ V) / rowsum, 16 x 8 x 4 = 512 tiles
    for (int t = bid; t < 512; t += nblk)
        gemm_tile<EPI_PV>(As, Bs, tid, (t >> 3) & 15, t & 7, t >> 7,
                          expS, VT, nullptr, nullptr, O1, DIM, SEQ, 1.0f, SS, (long)DIM * SEQ, SD);
    grid.sync();

    // ---- phase 4: out = O1 @ Wo^T + bo (fp32), 64 x 8 = 512 tiles
    for (int t = bid; t < 512; t += nblk)
        gemm_tile<EPI_OUT>(As, Bs, tid, t >> 3, t & 7, 0,
                           O1, Woh, bo, out, nullptr, DIM, DIM, 1.0f, 0, 0, 0);
}

extern "C" void kernel_launch(void* const* d_in, const int* in_sizes, int n_in,
                              void* d_out, int out_size, void* d_ws, size_t ws_size,
                              hipStream_t stream)
{
    const float* x  = (const float*)d_in[0];
    const float* Wq = (const float*)d_in[1];
    const float* bq = (const float*)d_in[2];
    const float* Wk = (const float*)d_in[3];
    const float* bk = (const float*)d_in[4];
    const float* Wv = (const float*)d_in[5];
    const float* bv = (const float*)d_in[6];
    const float* Wo = (const float*)d_in[7];
    const float* bo = (const float*)d_in[8];
    float* out = (float*)d_out;
    void* ws = d_ws;

    // co-residency capacity (host-side query; deterministic, capture-safe)
    int maxb = 2;
    (void)hipOccupancyMaxActiveBlocksPerMultiprocessor(&maxb, (const void*)mega, 256, 0);
    if (maxb < 1) maxb = 1;
    if (maxb > 4) maxb = 4;
    int nblk = 256 * maxb;   // <= 1024

    void* args[] = { (void*)&x, (void*)&Wq, (void*)&bq, (void*)&Wk, (void*)&bk,
                     (void*)&Wv, (void*)&bv, (void*)&Wo, (void*)&bo, (void*)&ws, (void*)&out };
    hipLaunchCooperativeKernel((const void*)mega, dim3(nblk), dim3(256), args, 0, stream);
}